// Round 1
// baseline (4307.929 us; speedup 1.0000x reference)
//
#include <hip/hip_runtime.h>
#include <cmath>

namespace {

constexpr int BB = 8192;
constexpr int TT = 512;
constexpr int FF = 2048;
constexpr float EPS_LN  = 1e-5f;
constexpr float EPS_SIG = 1e-8f;

__device__ __forceinline__ float silu_f(float v) {
    return v / (1.0f + expf(-v));
}

// ---------------- tokenizer: Q[b,t] = silu(x . l1_w[t] + l1_b[t]) ----------------
__global__ __launch_bounds__(256) void tok_kernel(
    const float* __restrict__ x, const float* __restrict__ l1w,
    const float* __restrict__ l1b, float* __restrict__ Q) {
    int idx = blockIdx.x * 256 + threadIdx.x;          // < B*T
    int b = idx >> 9, t = idx & 511;
    float x0 = x[2 * b], x1 = x[2 * b + 1];
    float v = fmaf(x0, l1w[2 * t], fmaf(x1, l1w[2 * t + 1], l1b[t]));
    Q[idx] = silu_f(v);
}

// ---------------- layernorm: one wave (64 lanes) per row of [B,512] ----------------
__global__ __launch_bounds__(256) void ln_kernel(
    const float* __restrict__ X, const float* __restrict__ g,
    const float* __restrict__ bia, float* __restrict__ Y) {
    int lane = threadIdx.x & 63;
    int row  = blockIdx.x * 4 + (threadIdx.x >> 6);
    const float* xr = X + (size_t)row * TT;
    float v[8];
    {
        float4 a = *(const float4*)(xr + lane * 8);
        float4 c = *(const float4*)(xr + lane * 8 + 4);
        v[0]=a.x; v[1]=a.y; v[2]=a.z; v[3]=a.w;
        v[4]=c.x; v[5]=c.y; v[6]=c.z; v[7]=c.w;
    }
    float s = 0.f;
    #pragma unroll
    for (int i = 0; i < 8; ++i) s += v[i];
    #pragma unroll
    for (int off = 32; off > 0; off >>= 1) s += __shfl_down(s, off);
    float mean = __shfl(s, 0) * (1.0f / TT);
    float ss = 0.f;
    #pragma unroll
    for (int i = 0; i < 8; ++i) { float d = v[i] - mean; ss = fmaf(d, d, ss); }
    #pragma unroll
    for (int off = 32; off > 0; off >>= 1) ss += __shfl_down(ss, off);
    float var  = __shfl(ss, 0) * (1.0f / TT);
    float rstd = rsqrtf(var + EPS_LN);
    float o[8];
    #pragma unroll
    for (int i = 0; i < 8; ++i) {
        int t = lane * 8 + i;
        o[i] = (v[i] - mean) * rstd * g[t] + bia[t];
    }
    float4* yp = (float4*)(Y + (size_t)row * TT + lane * 8);
    yp[0] = make_float4(o[0], o[1], o[2], o[3]);
    yp[1] = make_float4(o[4], o[5], o[6], o[7]);
}

// ---------------- GEMM: C[M,N] = act(A[M,K] @ W[N,K]^T + b) (+ residual) ----------------
// DUAL: two weight matrices sharing the A read (mu gets tanh, sig raw).
// ACT: 0 none, 1 silu, 2 tanh.  RESID: C1 = R + (A@W1^T + b1).
template <bool DUAL, int ACT, bool RESID>
__global__ __launch_bounds__(256) void gemm_kernel(
    const float* __restrict__ A, int K,
    const float* __restrict__ W1, const float* __restrict__ b1,
    const float* __restrict__ W2, const float* __restrict__ b2,
    const float* __restrict__ R,
    float* __restrict__ C1, float* __restrict__ C2, int N) {
    __shared__ float As[16][64];
    __shared__ float Ws1[16][64];
    __shared__ float Ws2[DUAL ? 16 : 1][64];

    int tid  = threadIdx.x;
    int m0   = blockIdx.x * 64;
    int n0   = blockIdx.y * 64;
    int lrow = tid >> 2;           // 0..63
    int lk   = (tid & 3) * 4;      // 0,4,8,12
    int tx   = tid & 15, ty = tid >> 4;

    const float* Aptr  = A  + (size_t)(m0 + lrow) * K + lk;
    const float* W1ptr = W1 + (size_t)(n0 + lrow) * K + lk;
    const float* W2ptr = nullptr;
    if (DUAL) W2ptr = W2 + (size_t)(n0 + lrow) * K + lk;

    float acc1[4][4] = {};
    float acc2[4][4] = {};

    for (int k0 = 0; k0 < K; k0 += 16) {
        float4 av  = *(const float4*)(Aptr + k0);
        float4 w1v = *(const float4*)(W1ptr + k0);
        As[lk + 0][lrow] = av.x;  As[lk + 1][lrow] = av.y;
        As[lk + 2][lrow] = av.z;  As[lk + 3][lrow] = av.w;
        Ws1[lk + 0][lrow] = w1v.x; Ws1[lk + 1][lrow] = w1v.y;
        Ws1[lk + 2][lrow] = w1v.z; Ws1[lk + 3][lrow] = w1v.w;
        if (DUAL) {
            float4 w2v = *(const float4*)(W2ptr + k0);
            Ws2[lk + 0][lrow] = w2v.x; Ws2[lk + 1][lrow] = w2v.y;
            Ws2[lk + 2][lrow] = w2v.z; Ws2[lk + 3][lrow] = w2v.w;
        }
        __syncthreads();
        #pragma unroll
        for (int kk = 0; kk < 16; ++kk) {
            float4 a4 = *(const float4*)&As[kk][ty * 4];
            float4 w4 = *(const float4*)&Ws1[kk][tx * 4];
            float av4[4] = {a4.x, a4.y, a4.z, a4.w};
            float wv4[4] = {w4.x, w4.y, w4.z, w4.w};
            #pragma unroll
            for (int i = 0; i < 4; ++i)
                #pragma unroll
                for (int j = 0; j < 4; ++j)
                    acc1[i][j] = fmaf(av4[i], wv4[j], acc1[i][j]);
            if (DUAL) {
                float4 u4 = *(const float4*)&Ws2[kk][tx * 4];
                float uv4[4] = {u4.x, u4.y, u4.z, u4.w};
                #pragma unroll
                for (int i = 0; i < 4; ++i)
                    #pragma unroll
                    for (int j = 0; j < 4; ++j)
                        acc2[i][j] = fmaf(av4[i], uv4[j], acc2[i][j]);
            }
        }
        __syncthreads();
    }

    #pragma unroll
    for (int i = 0; i < 4; ++i) {
        int row = m0 + ty * 4 + i;
        #pragma unroll
        for (int j = 0; j < 4; ++j) {
            int col = n0 + tx * 4 + j;
            float v = acc1[i][j] + b1[col];
            if (ACT == 1) v = silu_f(v);
            if (ACT == 2) v = tanhf(v);
            if (RESID) v += R[(size_t)row * N + col];
            C1[(size_t)row * N + col] = v;
            if (DUAL) C2[(size_t)row * N + col] = acc2[i][j] + b2[col];
        }
    }
}

// ------- Gaussian kernelized attention update: Q += sum_k S(G,mu,sig)*H -------
__global__ __launch_bounds__(256) void attn_kernel(
    float* __restrict__ Q, const float* __restrict__ mu_,
    const float* __restrict__ sig_, const float* __restrict__ x,
    const float* __restrict__ omega, const float* __restrict__ G,
    const float* __restrict__ phase) {
    int idx = blockIdx.x * 256 + threadIdx.x;          // < B*T
    int b = idx >> 9, t = idx & 511;
    float x0 = x[2 * b], x1 = x[2 * b + 1];
    float mu  = mu_[idx];
    float sig = sig_[idx];
    float inv = -0.5f / (fmaf(sig, sig, EPS_SIG));
    float acc = 0.f;
    #pragma unroll
    for (int k = 0; k < 8; ++k) {
        int e = t * 8 + k;
        float o0 = omega[2 * e], o1 = omega[2 * e + 1];
        float hv = cosf(fmaf(o0, x0, fmaf(o1, x1, phase[e])));
        float d  = G[e] - mu;
        acc = fmaf(expf(d * d * inv), hv, acc);
    }
    Q[idx] += acc;
}

// ---------------- readout: out[b] = silu(Q[b,:]) . ro_w + ro_b ----------------
__global__ __launch_bounds__(256) void readout_kernel(
    const float* __restrict__ Q, const float* __restrict__ row_,
    const float* __restrict__ rob, float* __restrict__ out) {
    int lane = threadIdx.x & 63;
    int row  = blockIdx.x * 4 + (threadIdx.x >> 6);
    const float* qr = Q + (size_t)row * TT;
    float acc = 0.f;
    #pragma unroll
    for (int i = 0; i < 8; ++i) {
        int t = lane * 8 + i;
        acc = fmaf(silu_f(qr[t]), row_[t], acc);
    }
    #pragma unroll
    for (int off = 32; off > 0; off >>= 1) acc += __shfl_down(acc, off);
    if (lane == 0) out[row] = acc + rob[0];
}

} // namespace

extern "C" void kernel_launch(void* const* d_in, const int* in_sizes, int n_in,
                              void* d_out, int out_size, void* d_ws, size_t ws_size,
                              hipStream_t stream) {
    const float* x     = (const float*)d_in[0];
    const float* omega = (const float*)d_in[1];
    const float* G     = (const float*)d_in[2];
    const float* phase = (const float*)d_in[3];
    const float* l1_w  = (const float*)d_in[4];
    const float* l1_b  = (const float*)d_in[5];
    const float* mu_w  = (const float*)d_in[6];
    const float* mu_b  = (const float*)d_in[7];
    const float* sg_w  = (const float*)d_in[8];
    const float* sg_b  = (const float*)d_in[9];
    const float* alqg  = (const float*)d_in[10];
    const float* alqb  = (const float*)d_in[11];
    const float* alfg  = (const float*)d_in[12];
    const float* alfb  = (const float*)d_in[13];
    const float* a_w1  = (const float*)d_in[14];
    const float* a_b1  = (const float*)d_in[15];
    const float* a_w2  = (const float*)d_in[16];
    const float* a_b2  = (const float*)d_in[17];
    const float* mln_g = (const float*)d_in[18];
    const float* mln_b = (const float*)d_in[19];
    const float* m_w1  = (const float*)d_in[20];
    const float* m_b1  = (const float*)d_in[21];
    const float* m_w2  = (const float*)d_in[22];
    const float* m_b2  = (const float*)d_in[23];
    const float* ro_w  = (const float*)d_in[24];
    const float* ro_b  = (const float*)d_in[25];

    const size_t BT = (size_t)BB * TT;           // 4,194,304
    float* Q   = (float*)d_ws;                   // [B,T]
    float* h   = Q + BT;                         // [B,T]
    float* mid = h + BT;                         // [B,F]  (64 MB)
    float* mu  = mid;                            // alias: [B,T] during attention
    float* sig = mid + BT;                       // alias: [B,T] during attention

    dim3 blk(256);

    tok_kernel<<<BB * TT / 256, blk, 0, stream>>>(x, l1_w, l1_b, Q);

    for (int i = 0; i < 4; ++i) {
        ln_kernel<<<BB / 4, blk, 0, stream>>>(Q, alqg + i * TT, alqb + i * TT, h);
        gemm_kernel<true, 2, false><<<dim3(BB / 64, TT / 64), blk, 0, stream>>>(
            h, TT, mu_w + (size_t)i * TT * TT, mu_b + i * TT,
            sg_w + (size_t)i * TT * TT, sg_b + i * TT,
            nullptr, mu, sig, TT);
        attn_kernel<<<BB * TT / 256, blk, 0, stream>>>(Q, mu, sig, x, omega, G, phase);
        ln_kernel<<<BB / 4, blk, 0, stream>>>(Q, alfg + i * TT, alfb + i * TT, h);
        gemm_kernel<false, 1, false><<<dim3(BB / 64, FF / 64), blk, 0, stream>>>(
            h, TT, a_w1 + (size_t)i * FF * TT, a_b1 + i * FF,
            nullptr, nullptr, nullptr, mid, nullptr, FF);
        gemm_kernel<false, 0, true><<<dim3(BB / 64, TT / 64), blk, 0, stream>>>(
            mid, FF, a_w2 + (size_t)i * TT * FF, a_b2 + i * TT,
            nullptr, nullptr, Q, Q, nullptr, TT);
    }
    for (int i = 0; i < 2; ++i) {
        ln_kernel<<<BB / 4, blk, 0, stream>>>(Q, mln_g + i * TT, mln_b + i * TT, h);
        gemm_kernel<false, 1, false><<<dim3(BB / 64, FF / 64), blk, 0, stream>>>(
            h, TT, m_w1 + (size_t)i * FF * TT, m_b1 + i * FF,
            nullptr, nullptr, nullptr, mid, nullptr, FF);
        gemm_kernel<false, 0, true><<<dim3(BB / 64, TT / 64), blk, 0, stream>>>(
            mid, FF, m_w2 + (size_t)i * TT * FF, m_b2 + i * TT,
            nullptr, nullptr, Q, Q, nullptr, TT);
    }

    readout_kernel<<<BB / 4, blk, 0, stream>>>(Q, ro_w, ro_b, (float*)d_out);
}

// Round 2
// 1447.169 us; speedup vs baseline: 2.9768x; 2.9768x over previous
//
#include <hip/hip_runtime.h>
#include <cmath>

namespace {

constexpr int BB = 8192;
constexpr int TT = 512;
constexpr int FF = 2048;
constexpr float EPS_LN  = 1e-5f;
constexpr float EPS_SIG = 1e-8f;

typedef _Float16 half8 __attribute__((ext_vector_type(8)));
typedef _Float16 half4 __attribute__((ext_vector_type(4)));
typedef float f32x4 __attribute__((ext_vector_type(4)));

typedef __attribute__((address_space(1))) void gvoid_t;
typedef __attribute__((address_space(3))) void lvoid_t;

__device__ __forceinline__ void async16(void* lds, const void* g) {
    __builtin_amdgcn_global_load_lds((gvoid_t*)g, (lvoid_t*)lds, 16, 0, 0);
}

__device__ __forceinline__ float silu_f(float v) {
    return v / (1.0f + expf(-v));
}

// ------------- fp32 -> f16 (hi, optional lo residual) weight conversion -------------
template <bool LO>
__global__ __launch_bounds__(256) void cvt_kernel(
    const float* __restrict__ s, _Float16* __restrict__ hi,
    _Float16* __restrict__ lo, int n) {
    int i = (blockIdx.x * 256 + threadIdx.x) * 4;
    if (i >= n) return;
    float4 v = *(const float4*)(s + i);
    half4 h;
    h[0] = (_Float16)v.x; h[1] = (_Float16)v.y;
    h[2] = (_Float16)v.z; h[3] = (_Float16)v.w;
    *(half4*)(hi + i) = h;
    if (LO) {
        half4 l;
        l[0] = (_Float16)(v.x - (float)h[0]);
        l[1] = (_Float16)(v.y - (float)h[1]);
        l[2] = (_Float16)(v.z - (float)h[2]);
        l[3] = (_Float16)(v.w - (float)h[3]);
        *(half4*)(lo + i) = l;
    }
}

// ---------------- tokenizer: Q[b,t] = silu(x . l1_w[t] + l1_b[t]) ----------------
__global__ __launch_bounds__(256) void tok_kernel(
    const float* __restrict__ x, const float* __restrict__ l1w,
    const float* __restrict__ l1b, float* __restrict__ Q) {
    int idx = blockIdx.x * 256 + threadIdx.x;          // < B*T
    int b = idx >> 9, t = idx & 511;
    float x0 = x[2 * b], x1 = x[2 * b + 1];
    float v = fmaf(x0, l1w[2 * t], fmaf(x1, l1w[2 * t + 1], l1b[t]));
    Q[idx] = silu_f(v);
}

// ------- layernorm (fp32 in, f16 out, optional f16 lo residual), wave per row -------
template <bool LO>
__global__ __launch_bounds__(256) void ln_kernel(
    const float* __restrict__ X, const float* __restrict__ g,
    const float* __restrict__ bia, _Float16* __restrict__ Y,
    _Float16* __restrict__ Ylo) {
    int lane = threadIdx.x & 63;
    int row  = blockIdx.x * 4 + (threadIdx.x >> 6);
    const float* xr = X + (size_t)row * TT;
    float v[8];
    {
        float4 a = *(const float4*)(xr + lane * 8);
        float4 c = *(const float4*)(xr + lane * 8 + 4);
        v[0]=a.x; v[1]=a.y; v[2]=a.z; v[3]=a.w;
        v[4]=c.x; v[5]=c.y; v[6]=c.z; v[7]=c.w;
    }
    float s = 0.f;
    #pragma unroll
    for (int i = 0; i < 8; ++i) s += v[i];
    #pragma unroll
    for (int off = 32; off > 0; off >>= 1) s += __shfl_down(s, off);
    float mean = __shfl(s, 0) * (1.0f / TT);
    float ss = 0.f;
    #pragma unroll
    for (int i = 0; i < 8; ++i) { float d = v[i] - mean; ss = fmaf(d, d, ss); }
    #pragma unroll
    for (int off = 32; off > 0; off >>= 1) ss += __shfl_down(ss, off);
    float var  = __shfl(ss, 0) * (1.0f / TT);
    float rstd = rsqrtf(var + EPS_LN);
    half8 hv, lv;
    #pragma unroll
    for (int i = 0; i < 8; ++i) {
        int t = lane * 8 + i;
        float o = (v[i] - mean) * rstd * g[t] + bia[t];
        hv[i] = (_Float16)o;
        if (LO) lv[i] = (_Float16)(o - (float)hv[i]);
    }
    *(half8*)(Y + (size_t)row * TT + lane * 8) = hv;
    if (LO) *(half8*)(Ylo + (size_t)row * TT + lane * 8) = lv;
}

// --------------- MFMA GEMM: C[M,N] = act(A[M,K] @ W[N,K]^T + b) (+R) ---------------
// BM=128, BK=32, 4 waves in 2x2 grid, wave tile 64 x (BN/2), mfma 16x16x32 f16.
// SPLIT: acc = A@W + Alo@W + A@Wlo (near-fp32 precision from f16 inputs).
template <int BN, int ACT, bool RESID, bool SPLIT, typename OutT>
__global__ __launch_bounds__(256) void gemm16_kernel(
    const _Float16* __restrict__ A, const _Float16* __restrict__ Alo,
    const _Float16* __restrict__ W, const _Float16* __restrict__ Wlo,
    const float* __restrict__ bias, const float* __restrict__ R,
    OutT* __restrict__ C, int N, int K) {
    constexpr int BM = 128;
    constexpr int BK = 32;
    constexpr int WN = BN / 2;
    constexpr int MI = 4;            // 64/16
    constexpr int NI = WN / 16;      // 4 (BN=128) or 2 (BN=64)
    constexpr int NS = SPLIT ? 2 : 1;

    __shared__ alignas(16) _Float16 As[NS][BM][BK];
    __shared__ alignas(16) _Float16 Ws[NS][BN][BK];

    const int tid  = threadIdx.x;
    const int m0   = blockIdx.x * BM;
    const int n0   = blockIdx.y * BN;
    const int srow = tid >> 2;           // 0..63
    const int skof = (tid & 3) * 8;      // k element offset (8 halves = 16 B)

    const _Float16* Ag  = A + (size_t)(m0 + srow) * K + skof;
    const _Float16* Wg  = W + (size_t)(n0 + srow) * K + skof;
    const _Float16* Ag2 = SPLIT ? (Alo + (size_t)(m0 + srow) * K + skof) : nullptr;
    const _Float16* Wg2 = SPLIT ? (Wlo + (size_t)(n0 + srow) * K + skof) : nullptr;

    const int wv   = tid >> 6;
    const int wm   = (wv >> 1) * 64;
    const int wn   = (wv & 1) * WN;
    const int lane = tid & 63;
    const int fr   = lane & 15;          // row/col within 16-tile
    const int fk   = (lane >> 4) * 8;    // k offset of fragment

    const f32x4 vzero = {0.f, 0.f, 0.f, 0.f};
    f32x4 acc[MI][NI];
    #pragma unroll
    for (int mi = 0; mi < MI; ++mi)
        #pragma unroll
        for (int ni = 0; ni < NI; ++ni) acc[mi][ni] = vzero;

    for (int k0 = 0; k0 < K; k0 += BK) {
        // global -> LDS async staging, 16 B per lane, lds dest = wave base + lane*16
        async16(&As[0][srow][skof], Ag + k0);
        async16(&As[0][64 + srow][skof], Ag + (size_t)64 * K + k0);
        async16(&Ws[0][srow][skof], Wg + k0);
        if (BN == 128) async16(&Ws[0][64 + srow][skof], Wg + (size_t)64 * K + k0);
        if (SPLIT) {
            async16(&As[1][srow][skof], Ag2 + k0);
            async16(&As[1][64 + srow][skof], Ag2 + (size_t)64 * K + k0);
            async16(&Ws[1][srow][skof], Wg2 + k0);
            if (BN == 128) async16(&Ws[1][64 + srow][skof], Wg2 + (size_t)64 * K + k0);
        }
        __syncthreads();

        half8 a[MI], b[NI];
        #pragma unroll
        for (int mi = 0; mi < MI; ++mi)
            a[mi] = *(const half8*)&As[0][wm + mi * 16 + fr][fk];
        #pragma unroll
        for (int ni = 0; ni < NI; ++ni)
            b[ni] = *(const half8*)&Ws[0][wn + ni * 16 + fr][fk];
        #pragma unroll
        for (int mi = 0; mi < MI; ++mi)
            #pragma unroll
            for (int ni = 0; ni < NI; ++ni)
                acc[mi][ni] = __builtin_amdgcn_mfma_f32_16x16x32_f16(
                    a[mi], b[ni], acc[mi][ni], 0, 0, 0);
        if (SPLIT) {
            half8 a2[MI], b2[NI];
            #pragma unroll
            for (int mi = 0; mi < MI; ++mi)
                a2[mi] = *(const half8*)&As[1][wm + mi * 16 + fr][fk];
            #pragma unroll
            for (int ni = 0; ni < NI; ++ni)
                b2[ni] = *(const half8*)&Ws[1][wn + ni * 16 + fr][fk];
            #pragma unroll
            for (int mi = 0; mi < MI; ++mi)
                #pragma unroll
                for (int ni = 0; ni < NI; ++ni)
                    acc[mi][ni] = __builtin_amdgcn_mfma_f32_16x16x32_f16(
                        a2[mi], b[ni], acc[mi][ni], 0, 0, 0);
            #pragma unroll
            for (int mi = 0; mi < MI; ++mi)
                #pragma unroll
                for (int ni = 0; ni < NI; ++ni)
                    acc[mi][ni] = __builtin_amdgcn_mfma_f32_16x16x32_f16(
                        a[mi], b2[ni], acc[mi][ni], 0, 0, 0);
        }
        __syncthreads();
    }

    // C/D layout: col = lane&15, row = (lane>>4)*4 + reg
    const int r0 = (lane >> 4) * 4;
    #pragma unroll
    for (int mi = 0; mi < MI; ++mi) {
        #pragma unroll
        for (int ni = 0; ni < NI; ++ni) {
            const int col = n0 + wn + ni * 16 + fr;
            const float bv = bias[col];
            #pragma unroll
            for (int r = 0; r < 4; ++r) {
                const int row = m0 + wm + mi * 16 + r0 + r;
                float v = acc[mi][ni][r] + bv;
                if (ACT == 1) v = silu_f(v);
                if (ACT == 2) v = tanhf(v);
                if (RESID) v += R[(size_t)row * N + col];
                C[(size_t)row * N + col] = (OutT)v;
            }
        }
    }
}

// ------- Gaussian kernelized attention update: Q += sum_k S(G,mu,sig)*H -------
__global__ __launch_bounds__(256) void attn_kernel(
    float* __restrict__ Q, const float* __restrict__ mu_,
    const float* __restrict__ sig_, const float* __restrict__ x,
    const float* __restrict__ omega, const float* __restrict__ G,
    const float* __restrict__ phase) {
    int idx = blockIdx.x * 256 + threadIdx.x;          // < B*T
    int b = idx >> 9, t = idx & 511;
    float x0 = x[2 * b], x1 = x[2 * b + 1];
    float mu  = mu_[idx];
    float sig = sig_[idx];
    float inv = -0.5f / (fmaf(sig, sig, EPS_SIG));
    float acc = 0.f;
    #pragma unroll
    for (int k = 0; k < 8; ++k) {
        int e = t * 8 + k;
        float o0 = omega[2 * e], o1 = omega[2 * e + 1];
        float hv = cosf(fmaf(o0, x0, fmaf(o1, x1, phase[e])));
        float d  = G[e] - mu;
        acc = fmaf(expf(d * d * inv), hv, acc);
    }
    Q[idx] += acc;
}

// ---------------- readout: out[b] = silu(Q[b,:]) . ro_w + ro_b ----------------
__global__ __launch_bounds__(256) void readout_kernel(
    const float* __restrict__ Q, const float* __restrict__ row_,
    const float* __restrict__ rob, float* __restrict__ out) {
    int lane = threadIdx.x & 63;
    int row  = blockIdx.x * 4 + (threadIdx.x >> 6);
    const float* qr = Q + (size_t)row * TT;
    float acc = 0.f;
    #pragma unroll
    for (int i = 0; i < 8; ++i) {
        int t = lane * 8 + i;
        acc = fmaf(silu_f(qr[t]), row_[t], acc);
    }
    #pragma unroll
    for (int off = 32; off > 0; off >>= 1) acc += __shfl_down(acc, off);
    if (lane == 0) out[row] = acc + rob[0];
}

} // namespace

extern "C" void kernel_launch(void* const* d_in, const int* in_sizes, int n_in,
                              void* d_out, int out_size, void* d_ws, size_t ws_size,
                              hipStream_t stream) {
    const float* x     = (const float*)d_in[0];
    const float* omega = (const float*)d_in[1];
    const float* G     = (const float*)d_in[2];
    const float* phase = (const float*)d_in[3];
    const float* l1_w  = (const float*)d_in[4];
    const float* l1_b  = (const float*)d_in[5];
    const float* mu_w  = (const float*)d_in[6];
    const float* mu_b  = (const float*)d_in[7];
    const float* sg_w  = (const float*)d_in[8];
    const float* sg_b  = (const float*)d_in[9];
    const float* alqg  = (const float*)d_in[10];
    const float* alqb  = (const float*)d_in[11];
    const float* alfg  = (const float*)d_in[12];
    const float* alfb  = (const float*)d_in[13];
    const float* a_w1  = (const float*)d_in[14];
    const float* a_b1  = (const float*)d_in[15];
    const float* a_w2  = (const float*)d_in[16];
    const float* a_b2  = (const float*)d_in[17];
    const float* mln_g = (const float*)d_in[18];
    const float* mln_b = (const float*)d_in[19];
    const float* m_w1  = (const float*)d_in[20];
    const float* m_b1  = (const float*)d_in[21];
    const float* m_w2  = (const float*)d_in[22];
    const float* m_b2  = (const float*)d_in[23];
    const float* ro_w  = (const float*)d_in[24];
    const float* ro_b  = (const float*)d_in[25];

    // ---- workspace layout (total 100,663,296 B == round-1 proven footprint) ----
    char* ws = (char*)d_ws;
    float*     Q    = (float*)ws;                          // 16 MB  [B,T] fp32
    _Float16*  h_hi = (_Float16*)(ws + 16777216);          //  8 MB  [B,T] f16
    _Float16*  h_lo = (_Float16*)(ws + 25165824);          //  8 MB  [B,T] f16
    _Float16*  mid  = (_Float16*)(ws + 33554432);          // 32 MB  [B,F] f16
    float*     mu   = (float*)(ws + 33554432);             // alias on mid
    float*     sig  = (float*)(ws + 50331648);             // alias on mid
    _Float16*  wbuf = (_Float16*)(ws + 67108864);          // 32 MB  f16 weights

    _Float16* muw_hi = wbuf;                     // 4*512*512
    _Float16* muw_lo = muw_hi + 1048576;
    _Float16* sgw_hi = muw_lo + 1048576;
    _Float16* sgw_lo = sgw_hi + 1048576;
    _Float16* aw1    = sgw_lo + 1048576;         // 4*2048*512
    _Float16* aw2    = aw1 + 4194304;
    _Float16* mw1    = aw2 + 4194304;            // 2*2048*512
    _Float16* mw2    = mw1 + 2097152;

    dim3 blk(256);

    // weight conversion (re-done every call; inputs are re-poisoned by harness)
    cvt_kernel<true ><<<1024, blk, 0, stream>>>(mu_w, muw_hi, muw_lo, 1048576);
    cvt_kernel<true ><<<1024, blk, 0, stream>>>(sg_w, sgw_hi, sgw_lo, 1048576);
    cvt_kernel<false><<<4096, blk, 0, stream>>>(a_w1, aw1, nullptr, 4194304);
    cvt_kernel<false><<<4096, blk, 0, stream>>>(a_w2, aw2, nullptr, 4194304);
    cvt_kernel<false><<<2048, blk, 0, stream>>>(m_w1, mw1, nullptr, 2097152);
    cvt_kernel<false><<<2048, blk, 0, stream>>>(m_w2, mw2, nullptr, 2097152);

    tok_kernel<<<BB * TT / 256, blk, 0, stream>>>(x, l1_w, l1_b, Q);

    for (int i = 0; i < 4; ++i) {
        ln_kernel<true><<<BB / 4, blk, 0, stream>>>(
            Q, alqg + i * TT, alqb + i * TT, h_hi, h_lo);
        gemm16_kernel<64, 2, false, true, float><<<dim3(BB / 128, TT / 64), blk, 0, stream>>>(
            h_hi, h_lo, muw_hi + (size_t)i * 262144, muw_lo + (size_t)i * 262144,
            mu_b + i * TT, nullptr, mu, TT, TT);
        gemm16_kernel<64, 0, false, true, float><<<dim3(BB / 128, TT / 64), blk, 0, stream>>>(
            h_hi, h_lo, sgw_hi + (size_t)i * 262144, sgw_lo + (size_t)i * 262144,
            sg_b + i * TT, nullptr, sig, TT, TT);
        attn_kernel<<<BB * TT / 256, blk, 0, stream>>>(Q, mu, sig, x, omega, G, phase);
        ln_kernel<false><<<BB / 4, blk, 0, stream>>>(
            Q, alfg + i * TT, alfb + i * TT, h_hi, nullptr);
        gemm16_kernel<128, 1, false, false, _Float16><<<dim3(BB / 128, FF / 128), blk, 0, stream>>>(
            h_hi, nullptr, aw1 + (size_t)i * 1048576, nullptr,
            a_b1 + i * FF, nullptr, mid, FF, TT);
        gemm16_kernel<64, 0, true, false, float><<<dim3(BB / 128, TT / 64), blk, 0, stream>>>(
            mid, nullptr, aw2 + (size_t)i * 1048576, nullptr,
            a_b2 + i * TT, Q, Q, TT, FF);
    }
    for (int i = 0; i < 2; ++i) {
        ln_kernel<false><<<BB / 4, blk, 0, stream>>>(
            Q, mln_g + i * TT, mln_b + i * TT, h_hi, nullptr);
        gemm16_kernel<128, 1, false, false, _Float16><<<dim3(BB / 128, FF / 128), blk, 0, stream>>>(
            h_hi, nullptr, mw1 + (size_t)i * 1048576, nullptr,
            m_b1 + i * FF, nullptr, mid, FF, TT);
        gemm16_kernel<64, 0, true, false, float><<<dim3(BB / 128, TT / 64), blk, 0, stream>>>(
            mid, nullptr, mw2 + (size_t)i * 1048576, nullptr,
            m_b2 + i * TT, Q, Q, TT, FF);
    }

    readout_kernel<<<BB / 4, blk, 0, stream>>>(Q, ro_w, ro_b, (float*)d_out);
}

// Round 3
// 989.931 us; speedup vs baseline: 4.3517x; 1.4619x over previous
//
#include <hip/hip_runtime.h>
#include <cmath>

namespace {

constexpr int BB = 8192;
constexpr int TT = 512;
constexpr int FF = 2048;
constexpr float EPS_LN  = 1e-5f;
constexpr float EPS_SIG = 1e-8f;

typedef _Float16 half8 __attribute__((ext_vector_type(8)));
typedef _Float16 half4 __attribute__((ext_vector_type(4)));
typedef float f32x4 __attribute__((ext_vector_type(4)));

typedef __attribute__((address_space(1))) void gvoid_t;
typedef __attribute__((address_space(3))) void lvoid_t;

__device__ __forceinline__ void async16(void* lds, const void* g) {
    __builtin_amdgcn_global_load_lds((gvoid_t*)g, (lvoid_t*)lds, 16, 0, 0);
}

__device__ __forceinline__ float silu_f(float v) {
    return v / (1.0f + expf(-v));
}

// ------------- fp32 -> f16 (hi, optional lo residual) weight conversion -------------
template <bool LO>
__global__ __launch_bounds__(256) void cvt_kernel(
    const float* __restrict__ s, _Float16* __restrict__ hi,
    _Float16* __restrict__ lo, int n) {
    int i = (blockIdx.x * 256 + threadIdx.x) * 4;
    if (i >= n) return;
    float4 v = *(const float4*)(s + i);
    half4 h;
    h[0] = (_Float16)v.x; h[1] = (_Float16)v.y;
    h[2] = (_Float16)v.z; h[3] = (_Float16)v.w;
    *(half4*)(hi + i) = h;
    if (LO) {
        half4 l;
        l[0] = (_Float16)(v.x - (float)h[0]);
        l[1] = (_Float16)(v.y - (float)h[1]);
        l[2] = (_Float16)(v.z - (float)h[2]);
        l[3] = (_Float16)(v.w - (float)h[3]);
        *(half4*)(lo + i) = l;
    }
}

// ---------------- tokenizer: Q[b,t] = silu(x . l1_w[t] + l1_b[t]) ----------------
__global__ __launch_bounds__(256) void tok_kernel(
    const float* __restrict__ x, const float* __restrict__ l1w,
    const float* __restrict__ l1b, float* __restrict__ Q) {
    int idx = blockIdx.x * 256 + threadIdx.x;          // < B*T
    int b = idx >> 9, t = idx & 511;
    float x0 = x[2 * b], x1 = x[2 * b + 1];
    float v = fmaf(x0, l1w[2 * t], fmaf(x1, l1w[2 * t + 1], l1b[t]));
    Q[idx] = silu_f(v);
}

// ------- layernorm (fp32 in, f16 out, optional f16 lo residual), wave per row -------
template <bool LO>
__global__ __launch_bounds__(256) void ln_kernel(
    const float* __restrict__ X, const float* __restrict__ g,
    const float* __restrict__ bia, _Float16* __restrict__ Y,
    _Float16* __restrict__ Ylo) {
    int lane = threadIdx.x & 63;
    int row  = blockIdx.x * 4 + (threadIdx.x >> 6);
    const float* xr = X + (size_t)row * TT;
    float v[8];
    {
        float4 a = *(const float4*)(xr + lane * 8);
        float4 c = *(const float4*)(xr + lane * 8 + 4);
        v[0]=a.x; v[1]=a.y; v[2]=a.z; v[3]=a.w;
        v[4]=c.x; v[5]=c.y; v[6]=c.z; v[7]=c.w;
    }
    float s = 0.f;
    #pragma unroll
    for (int i = 0; i < 8; ++i) s += v[i];
    #pragma unroll
    for (int off = 32; off > 0; off >>= 1) s += __shfl_down(s, off);
    float mean = __shfl(s, 0) * (1.0f / TT);
    float ss = 0.f;
    #pragma unroll
    for (int i = 0; i < 8; ++i) { float d = v[i] - mean; ss = fmaf(d, d, ss); }
    #pragma unroll
    for (int off = 32; off > 0; off >>= 1) ss += __shfl_down(ss, off);
    float var  = __shfl(ss, 0) * (1.0f / TT);
    float rstd = rsqrtf(var + EPS_LN);
    half8 hv, lv;
    #pragma unroll
    for (int i = 0; i < 8; ++i) {
        int t = lane * 8 + i;
        float o = (v[i] - mean) * rstd * g[t] + bia[t];
        hv[i] = (_Float16)o;
        if (LO) lv[i] = (_Float16)(o - (float)hv[i]);
    }
    *(half8*)(Y + (size_t)row * TT + lane * 8) = hv;
    if (LO) *(half8*)(Ylo + (size_t)row * TT + lane * 8) = lv;
}

// --------------- MFMA GEMM: C[M,N] = act(A[M,K] @ W[N,K]^T + b) (+R) ---------------
// BM=128, BK=32, 4 waves in 2x2 grid, wave tile 64 x (BN/2), mfma 16x16x32 f16.
// SPLIT: acc = A@W + Alo@W + A@Wlo (near-fp32 precision from f16 inputs).
template <int BN, int ACT, bool RESID, bool SPLIT, typename OutT>
__global__ __launch_bounds__(256) void gemm16_kernel(
    const _Float16* __restrict__ A, const _Float16* __restrict__ Alo,
    const _Float16* __restrict__ W, const _Float16* __restrict__ Wlo,
    const float* __restrict__ bias, const float* __restrict__ R,
    OutT* __restrict__ C, int N, int K) {
    constexpr int BM = 128;
    constexpr int BK = 32;
    constexpr int WN = BN / 2;
    constexpr int MI = 4;            // 64/16
    constexpr int NI = WN / 16;      // 4 (BN=128) or 2 (BN=64)
    constexpr int NS = SPLIT ? 2 : 1;

    __shared__ alignas(16) _Float16 As[NS][BM][BK];
    __shared__ alignas(16) _Float16 Ws[NS][BN][BK];

    const int tid  = threadIdx.x;
    const int m0   = blockIdx.x * BM;
    const int n0   = blockIdx.y * BN;
    const int srow = tid >> 2;           // 0..63
    const int skof = (tid & 3) * 8;      // k element offset (8 halves = 16 B)

    const _Float16* Ag  = A + (size_t)(m0 + srow) * K + skof;
    const _Float16* Wg  = W + (size_t)(n0 + srow) * K + skof;
    const _Float16* Ag2 = SPLIT ? (Alo + (size_t)(m0 + srow) * K + skof) : nullptr;
    const _Float16* Wg2 = SPLIT ? (Wlo + (size_t)(n0 + srow) * K + skof) : nullptr;

    const int wv   = tid >> 6;
    const int wm   = (wv >> 1) * 64;
    const int wn   = (wv & 1) * WN;
    const int lane = tid & 63;
    const int fr   = lane & 15;          // row/col within 16-tile
    const int fk   = (lane >> 4) * 8;    // k offset of fragment

    const f32x4 vzero = {0.f, 0.f, 0.f, 0.f};
    f32x4 acc[MI][NI];
    #pragma unroll
    for (int mi = 0; mi < MI; ++mi)
        #pragma unroll
        for (int ni = 0; ni < NI; ++ni) acc[mi][ni] = vzero;

    for (int k0 = 0; k0 < K; k0 += BK) {
        // global -> LDS async staging, 16 B per lane, lds dest = wave base + lane*16
        async16(&As[0][srow][skof], Ag + k0);
        async16(&As[0][64 + srow][skof], Ag + (size_t)64 * K + k0);
        async16(&Ws[0][srow][skof], Wg + k0);
        if (BN == 128) async16(&Ws[0][64 + srow][skof], Wg + (size_t)64 * K + k0);
        if (SPLIT) {
            async16(&As[1][srow][skof], Ag2 + k0);
            async16(&As[1][64 + srow][skof], Ag2 + (size_t)64 * K + k0);
            async16(&Ws[1][srow][skof], Wg2 + k0);
            if (BN == 128) async16(&Ws[1][64 + srow][skof], Wg2 + (size_t)64 * K + k0);
        }
        __syncthreads();

        half8 a[MI], b[NI];
        #pragma unroll
        for (int mi = 0; mi < MI; ++mi)
            a[mi] = *(const half8*)&As[0][wm + mi * 16 + fr][fk];
        #pragma unroll
        for (int ni = 0; ni < NI; ++ni)
            b[ni] = *(const half8*)&Ws[0][wn + ni * 16 + fr][fk];
        #pragma unroll
        for (int mi = 0; mi < MI; ++mi)
            #pragma unroll
            for (int ni = 0; ni < NI; ++ni)
                acc[mi][ni] = __builtin_amdgcn_mfma_f32_16x16x32_f16(
                    a[mi], b[ni], acc[mi][ni], 0, 0, 0);
        if (SPLIT) {
            half8 a2[MI], b2[NI];
            #pragma unroll
            for (int mi = 0; mi < MI; ++mi)
                a2[mi] = *(const half8*)&As[1][wm + mi * 16 + fr][fk];
            #pragma unroll
            for (int ni = 0; ni < NI; ++ni)
                b2[ni] = *(const half8*)&Ws[1][wn + ni * 16 + fr][fk];
            #pragma unroll
            for (int mi = 0; mi < MI; ++mi)
                #pragma unroll
                for (int ni = 0; ni < NI; ++ni)
                    acc[mi][ni] = __builtin_amdgcn_mfma_f32_16x16x32_f16(
                        a2[mi], b[ni], acc[mi][ni], 0, 0, 0);
            #pragma unroll
            for (int mi = 0; mi < MI; ++mi)
                #pragma unroll
                for (int ni = 0; ni < NI; ++ni)
                    acc[mi][ni] = __builtin_amdgcn_mfma_f32_16x16x32_f16(
                        a[mi], b2[ni], acc[mi][ni], 0, 0, 0);
        }
        __syncthreads();
    }

    // C/D layout: col = lane&15, row = (lane>>4)*4 + reg
    const int r0 = (lane >> 4) * 4;
    #pragma unroll
    for (int mi = 0; mi < MI; ++mi) {
        #pragma unroll
        for (int ni = 0; ni < NI; ++ni) {
            const int col = n0 + wn + ni * 16 + fr;
            const float bv = bias[col];
            #pragma unroll
            for (int r = 0; r < 4; ++r) {
                const int row = m0 + wm + mi * 16 + r0 + r;
                float v = acc[mi][ni][r] + bv;
                if (ACT == 1) v = silu_f(v);
                if (ACT == 2) v = tanhf(v);
                if (RESID) v += R[(size_t)row * N + col];
                C[(size_t)row * N + col] = (OutT)v;
            }
        }
    }
}

// ------- Gaussian kernelized attention update: Q += sum_k S(G,mu,sig)*H -------
// One block = one b-row half (256 tokens). x is wave-uniform per block.
// cos/G tables staged through LDS transposed [k][t] so the inner loop reads
// stride-4B (2 lanes/bank = conflict-free); staging loads are fully coalesced.
__global__ __launch_bounds__(256) void attn_kernel(
    float* __restrict__ Q, const float* __restrict__ mu_,
    const float* __restrict__ sig_, const float* __restrict__ x,
    const float* __restrict__ omega, const float* __restrict__ G,
    const float* __restrict__ phase) {
    __shared__ float cs[8][260];   // pad 260: staging writes spread banks
    __shared__ float gs[8][260];
    const int tid = threadIdx.x;
    const int b   = blockIdx.x >> 1;
    const int t0  = (blockIdx.x & 1) * 256;
    const float x0 = x[2 * b], x1 = x[2 * b + 1];
    #pragma unroll
    for (int it = 0; it < 8; ++it) {
        int j = it * 256 + tid;            // 0..2047
        int e = t0 * 8 + j;                // flat (t,k) index
        float2 om = *(const float2*)(omega + 2 * e);
        float arg = fmaf(om.x, x0, fmaf(om.y, x1, phase[e]));
        cs[j & 7][j >> 3] = __cosf(arg);
        gs[j & 7][j >> 3] = G[e];
    }
    __syncthreads();
    const int idx = blockIdx.x * 256 + tid;   // = b*512 + t0 + tid
    float mu  = mu_[idx];
    float sig = sig_[idx];
    float inv = -0.5f * __builtin_amdgcn_rcpf(fmaf(sig, sig, EPS_SIG));
    float acc = 0.f;
    #pragma unroll
    for (int k = 0; k < 8; ++k) {
        float d = gs[k][tid] - mu;
        acc = fmaf(__expf(d * d * inv), cs[k][tid], acc);
    }
    Q[idx] += acc;
}

// ---------------- readout: out[b] = silu(Q[b,:]) . ro_w + ro_b ----------------
__global__ __launch_bounds__(256) void readout_kernel(
    const float* __restrict__ Q, const float* __restrict__ row_,
    const float* __restrict__ rob, float* __restrict__ out) {
    int lane = threadIdx.x & 63;
    int row  = blockIdx.x * 4 + (threadIdx.x >> 6);
    const float* qr = Q + (size_t)row * TT;
    float acc = 0.f;
    #pragma unroll
    for (int i = 0; i < 8; ++i) {
        int t = lane * 8 + i;
        acc = fmaf(silu_f(qr[t]), row_[t], acc);
    }
    #pragma unroll
    for (int off = 32; off > 0; off >>= 1) acc += __shfl_down(acc, off);
    if (lane == 0) out[row] = acc + rob[0];
}

} // namespace

extern "C" void kernel_launch(void* const* d_in, const int* in_sizes, int n_in,
                              void* d_out, int out_size, void* d_ws, size_t ws_size,
                              hipStream_t stream) {
    const float* x     = (const float*)d_in[0];
    const float* omega = (const float*)d_in[1];
    const float* G     = (const float*)d_in[2];
    const float* phase = (const float*)d_in[3];
    const float* l1_w  = (const float*)d_in[4];
    const float* l1_b  = (const float*)d_in[5];
    const float* mu_w  = (const float*)d_in[6];
    const float* mu_b  = (const float*)d_in[7];
    const float* sg_w  = (const float*)d_in[8];
    const float* sg_b  = (const float*)d_in[9];
    const float* alqg  = (const float*)d_in[10];
    const float* alqb  = (const float*)d_in[11];
    const float* alfg  = (const float*)d_in[12];
    const float* alfb  = (const float*)d_in[13];
    const float* a_w1  = (const float*)d_in[14];
    const float* a_b1  = (const float*)d_in[15];
    const float* a_w2  = (const float*)d_in[16];
    const float* a_b2  = (const float*)d_in[17];
    const float* mln_g = (const float*)d_in[18];
    const float* mln_b = (const float*)d_in[19];
    const float* m_w1  = (const float*)d_in[20];
    const float* m_b1  = (const float*)d_in[21];
    const float* m_w2  = (const float*)d_in[22];
    const float* m_b2  = (const float*)d_in[23];
    const float* ro_w  = (const float*)d_in[24];
    const float* ro_b  = (const float*)d_in[25];

    // ---- workspace layout (total 100,663,296 B == round-1 proven footprint) ----
    char* ws = (char*)d_ws;
    float*     Q    = (float*)ws;                          // 16 MB  [B,T] fp32
    _Float16*  h_hi = (_Float16*)(ws + 16777216);          //  8 MB  [B,T] f16
    _Float16*  h_lo = (_Float16*)(ws + 25165824);          //  8 MB  [B,T] f16
    _Float16*  mid  = (_Float16*)(ws + 33554432);          // 32 MB  [B,F] f16
    float*     mu   = (float*)(ws + 33554432);             // alias on mid
    float*     sig  = (float*)(ws + 50331648);             // alias on mid
    _Float16*  wbuf = (_Float16*)(ws + 67108864);          // 32 MB  f16 weights

    _Float16* muw_hi = wbuf;                     // 4*512*512
    _Float16* muw_lo = muw_hi + 1048576;
    _Float16* sgw_hi = muw_lo + 1048576;
    _Float16* sgw_lo = sgw_hi + 1048576;
    _Float16* aw1    = sgw_lo + 1048576;         // 4*2048*512
    _Float16* aw2    = aw1 + 4194304;
    _Float16* mw1    = aw2 + 4194304;            // 2*2048*512
    _Float16* mw2    = mw1 + 2097152;

    dim3 blk(256);

    // weight conversion (re-done every call; inputs are re-poisoned by harness)
    cvt_kernel<true ><<<1024, blk, 0, stream>>>(mu_w, muw_hi, muw_lo, 1048576);
    cvt_kernel<true ><<<1024, blk, 0, stream>>>(sg_w, sgw_hi, sgw_lo, 1048576);
    cvt_kernel<false><<<4096, blk, 0, stream>>>(a_w1, aw1, nullptr, 4194304);
    cvt_kernel<false><<<4096, blk, 0, stream>>>(a_w2, aw2, nullptr, 4194304);
    cvt_kernel<false><<<2048, blk, 0, stream>>>(m_w1, mw1, nullptr, 2097152);
    cvt_kernel<false><<<2048, blk, 0, stream>>>(m_w2, mw2, nullptr, 2097152);

    tok_kernel<<<BB * TT / 256, blk, 0, stream>>>(x, l1_w, l1_b, Q);

    for (int i = 0; i < 4; ++i) {
        ln_kernel<true><<<BB / 4, blk, 0, stream>>>(
            Q, alqg + i * TT, alqb + i * TT, h_hi, h_lo);
        gemm16_kernel<64, 2, false, true, float><<<dim3(BB / 128, TT / 64), blk, 0, stream>>>(
            h_hi, h_lo, muw_hi + (size_t)i * 262144, muw_lo + (size_t)i * 262144,
            mu_b + i * TT, nullptr, mu, TT, TT);
        gemm16_kernel<64, 0, false, true, float><<<dim3(BB / 128, TT / 64), blk, 0, stream>>>(
            h_hi, h_lo, sgw_hi + (size_t)i * 262144, sgw_lo + (size_t)i * 262144,
            sg_b + i * TT, nullptr, sig, TT, TT);
        attn_kernel<<<BB * TT / 256, blk, 0, stream>>>(Q, mu, sig, x, omega, G, phase);
        ln_kernel<false><<<BB / 4, blk, 0, stream>>>(
            Q, alfg + i * TT, alfb + i * TT, h_hi, nullptr);
        gemm16_kernel<128, 1, false, false, _Float16><<<dim3(BB / 128, FF / 128), blk, 0, stream>>>(
            h_hi, nullptr, aw1 + (size_t)i * 1048576, nullptr,
            a_b1 + i * FF, nullptr, mid, FF, TT);
        gemm16_kernel<64, 0, true, false, float><<<dim3(BB / 128, TT / 64), blk, 0, stream>>>(
            mid, nullptr, aw2 + (size_t)i * 1048576, nullptr,
            a_b2 + i * TT, Q, Q, TT, FF);
    }
    for (int i = 0; i < 2; ++i) {
        ln_kernel<false><<<BB / 4, blk, 0, stream>>>(
            Q, mln_g + i * TT, mln_b + i * TT, h_hi, nullptr);
        gemm16_kernel<128, 1, false, false, _Float16><<<dim3(BB / 128, FF / 128), blk, 0, stream>>>(
            h_hi, nullptr, mw1 + (size_t)i * 1048576, nullptr,
            m_b1 + i * FF, nullptr, mid, FF, TT);
        gemm16_kernel<64, 0, true, false, float><<<dim3(BB / 128, TT / 64), blk, 0, stream>>>(
            mid, nullptr, mw2 + (size_t)i * 1048576, nullptr,
            m_b2 + i * TT, Q, Q, TT, FF);
    }

    readout_kernel<<<BB / 4, blk, 0, stream>>>(Q, ro_w, ro_b, (float*)d_out);
}

// Round 4
// 932.283 us; speedup vs baseline: 4.6208x; 1.0618x over previous
//
#include <hip/hip_runtime.h>
#include <cmath>

namespace {

constexpr int BB = 8192;
constexpr int TT = 512;
constexpr int FF = 2048;
constexpr float EPS_LN  = 1e-5f;
constexpr float EPS_SIG = 1e-8f;

typedef _Float16 half8 __attribute__((ext_vector_type(8)));
typedef _Float16 half4 __attribute__((ext_vector_type(4)));
typedef float f32x4 __attribute__((ext_vector_type(4)));

typedef __attribute__((address_space(1))) void gvoid_t;
typedef __attribute__((address_space(3))) void lvoid_t;

__device__ __forceinline__ void async16(void* lds, const void* g) {
    __builtin_amdgcn_global_load_lds((gvoid_t*)g, (lvoid_t*)lds, 16, 0, 0);
}

__device__ __forceinline__ float silu_f(float v) {
    return v / (1.0f + expf(-v));
}

// ------------- fp32 -> f16 (hi, optional lo residual) weight conversion -------------
template <bool LO>
__global__ __launch_bounds__(256) void cvt_kernel(
    const float* __restrict__ s, _Float16* __restrict__ hi,
    _Float16* __restrict__ lo, int n) {
    int i = (blockIdx.x * 256 + threadIdx.x) * 4;
    if (i >= n) return;
    float4 v = *(const float4*)(s + i);
    half4 h;
    h[0] = (_Float16)v.x; h[1] = (_Float16)v.y;
    h[2] = (_Float16)v.z; h[3] = (_Float16)v.w;
    *(half4*)(hi + i) = h;
    if (LO) {
        half4 l;
        l[0] = (_Float16)(v.x - (float)h[0]);
        l[1] = (_Float16)(v.y - (float)h[1]);
        l[2] = (_Float16)(v.z - (float)h[2]);
        l[3] = (_Float16)(v.w - (float)h[3]);
        *(half4*)(lo + i) = l;
    }
}

// ---------------- tokenizer: Q[b,t] = silu(x . l1_w[t] + l1_b[t]) ----------------
__global__ __launch_bounds__(256) void tok_kernel(
    const float* __restrict__ x, const float* __restrict__ l1w,
    const float* __restrict__ l1b, float* __restrict__ Q) {
    int idx = blockIdx.x * 256 + threadIdx.x;          // < B*T
    int b = idx >> 9, t = idx & 511;
    float x0 = x[2 * b], x1 = x[2 * b + 1];
    float v = fmaf(x0, l1w[2 * t], fmaf(x1, l1w[2 * t + 1], l1b[t]));
    Q[idx] = silu_f(v);
}

// ------- layernorm (fp32 in, f16 out, optional f16 lo residual), wave per row -------
template <bool LO>
__global__ __launch_bounds__(256) void ln_kernel(
    const float* __restrict__ X, const float* __restrict__ g,
    const float* __restrict__ bia, _Float16* __restrict__ Y,
    _Float16* __restrict__ Ylo) {
    int lane = threadIdx.x & 63;
    int row  = blockIdx.x * 4 + (threadIdx.x >> 6);
    const float* xr = X + (size_t)row * TT;
    float v[8];
    {
        float4 a = *(const float4*)(xr + lane * 8);
        float4 c = *(const float4*)(xr + lane * 8 + 4);
        v[0]=a.x; v[1]=a.y; v[2]=a.z; v[3]=a.w;
        v[4]=c.x; v[5]=c.y; v[6]=c.z; v[7]=c.w;
    }
    float s = 0.f;
    #pragma unroll
    for (int i = 0; i < 8; ++i) s += v[i];
    #pragma unroll
    for (int off = 32; off > 0; off >>= 1) s += __shfl_down(s, off);
    float mean = __shfl(s, 0) * (1.0f / TT);
    float ss = 0.f;
    #pragma unroll
    for (int i = 0; i < 8; ++i) { float d = v[i] - mean; ss = fmaf(d, d, ss); }
    #pragma unroll
    for (int off = 32; off > 0; off >>= 1) ss += __shfl_down(ss, off);
    float var  = __shfl(ss, 0) * (1.0f / TT);
    float rstd = rsqrtf(var + EPS_LN);
    half8 hv, lv;
    #pragma unroll
    for (int i = 0; i < 8; ++i) {
        int t = lane * 8 + i;
        float o = (v[i] - mean) * rstd * g[t] + bia[t];
        hv[i] = (_Float16)o;
        if (LO) lv[i] = (_Float16)(o - (float)hv[i]);
    }
    *(half8*)(Y + (size_t)row * TT + lane * 8) = hv;
    if (LO) *(half8*)(Ylo + (size_t)row * TT + lane * 8) = lv;
}

// --------------- MFMA GEMM: C[M,N] = act(A[M,K] @ W[N,K]^T + b) (+R) ---------------
// BM=128, BK=32, 4 waves 2x2, wave tile 64 x (BN/2), mfma 16x16x32 f16.
// Double-buffered LDS, ONE barrier per K-iter, staging issued after barrier so the
// vmcnt(0) drain at the NEXT barrier lands after a full compute phase.
// XOR chunk swizzle (source-side): store 16B-chunk c of row r at slot c^((r>>1)&3)
// -> fragment ds_read_b128 is 2-way-or-less bank aliased (free per m136).
// SPLIT: acc = A@W + Alo@W + A@Wlo (near-fp32 precision from f16 inputs).
template <int BN, int ACT, bool RESID, bool SPLIT, typename OutT>
__global__ __launch_bounds__(256) void gemm16_kernel(
    const _Float16* __restrict__ A, const _Float16* __restrict__ Alo,
    const _Float16* __restrict__ W, const _Float16* __restrict__ Wlo,
    const float* __restrict__ bias, const float* __restrict__ R,
    OutT* __restrict__ C, int N, int K) {
    constexpr int BM = 128;
    constexpr int BK = 32;
    constexpr int WN = BN / 2;
    constexpr int MI = 4;            // 64/16
    constexpr int NI = WN / 16;      // 4 (BN=128) or 2 (BN=64)
    constexpr int NS = SPLIT ? 2 : 1;

    __shared__ alignas(16) _Float16 As[2][NS][BM][BK];
    __shared__ alignas(16) _Float16 Ws[2][NS][BN][BK];

    const int tid  = threadIdx.x;
    const int m0   = blockIdx.x * BM;
    const int n0   = blockIdx.y * BN;

    // staging decomposition: flat 16B chunk i = j*256+tid -> row i>>2, slot i&3
    const int sr = tid >> 2;                 // row (within 64-row round)
    const int sc = tid & 3;                  // slot
    const int scs = sc ^ ((sr >> 1) & 3);    // swizzled source chunk

    const _Float16* Ag[NS];
    const _Float16* Wg[NS];
    Ag[0] = A + (size_t)(m0 + sr) * K + scs * 8;
    Wg[0] = W + (size_t)(n0 + sr) * K + scs * 8;
    if (SPLIT) {
        Ag[1] = Alo + (size_t)(m0 + sr) * K + scs * 8;
        Wg[1] = Wlo + (size_t)(n0 + sr) * K + scs * 8;
    }

    const int wv   = tid >> 6;
    const int wm   = (wv >> 1) * 64;
    const int wn   = (wv & 1) * WN;
    const int lane = tid & 63;
    const int fr   = lane & 15;          // row/col within 16-tile
    const int q    = lane >> 4;          // logical k-chunk of fragment
    const int fk   = (q ^ ((fr >> 1) & 3)) * 8;   // swizzled LDS k-offset (halves)

    const f32x4 vzero = {0.f, 0.f, 0.f, 0.f};
    f32x4 acc[MI][NI];
    #pragma unroll
    for (int mi = 0; mi < MI; ++mi)
        #pragma unroll
        for (int ni = 0; ni < NI; ++ni) acc[mi][ni] = vzero;

    auto stage = [&](int buf, int k0) {
        #pragma unroll
        for (int s = 0; s < NS; ++s) {
            async16(&As[buf][s][sr][sc * 8], Ag[s] + k0);
            async16(&As[buf][s][64 + sr][sc * 8], Ag[s] + (size_t)64 * K + k0);
            async16(&Ws[buf][s][sr][sc * 8], Wg[s] + k0);
            if (BN == 128)
                async16(&Ws[buf][s][64 + sr][sc * 8], Wg[s] + (size_t)64 * K + k0);
        }
    };

    stage(0, 0);
    const int NK = K / BK;
    for (int ki = 0; ki < NK; ++ki) {
        const int buf = ki & 1;
        __syncthreads();                       // drains prev stage (after full compute)
        if (ki + 1 < NK) stage(buf ^ 1, (ki + 1) * BK);

        half8 a[MI], b[NI];
        #pragma unroll
        for (int mi = 0; mi < MI; ++mi)
            a[mi] = *(const half8*)&As[buf][0][wm + mi * 16 + fr][fk];
        #pragma unroll
        for (int ni = 0; ni < NI; ++ni)
            b[ni] = *(const half8*)&Ws[buf][0][wn + ni * 16 + fr][fk];
        #pragma unroll
        for (int mi = 0; mi < MI; ++mi)
            #pragma unroll
            for (int ni = 0; ni < NI; ++ni)
                acc[mi][ni] = __builtin_amdgcn_mfma_f32_16x16x32_f16(
                    a[mi], b[ni], acc[mi][ni], 0, 0, 0);
        if (SPLIT) {
            half8 a2[MI], b2[NI];
            #pragma unroll
            for (int mi = 0; mi < MI; ++mi)
                a2[mi] = *(const half8*)&As[buf][1][wm + mi * 16 + fr][fk];
            #pragma unroll
            for (int ni = 0; ni < NI; ++ni)
                b2[ni] = *(const half8*)&Ws[buf][1][wn + ni * 16 + fr][fk];
            #pragma unroll
            for (int mi = 0; mi < MI; ++mi)
                #pragma unroll
                for (int ni = 0; ni < NI; ++ni)
                    acc[mi][ni] = __builtin_amdgcn_mfma_f32_16x16x32_f16(
                        a2[mi], b[ni], acc[mi][ni], 0, 0, 0);
            #pragma unroll
            for (int mi = 0; mi < MI; ++mi)
                #pragma unroll
                for (int ni = 0; ni < NI; ++ni)
                    acc[mi][ni] = __builtin_amdgcn_mfma_f32_16x16x32_f16(
                        a[mi], b2[ni], acc[mi][ni], 0, 0, 0);
        }
    }

    // C/D layout: col = lane&15, row = (lane>>4)*4 + reg
    const int r0 = (lane >> 4) * 4;
    #pragma unroll
    for (int mi = 0; mi < MI; ++mi) {
        #pragma unroll
        for (int ni = 0; ni < NI; ++ni) {
            const int col = n0 + wn + ni * 16 + fr;
            const float bv = bias[col];
            #pragma unroll
            for (int r = 0; r < 4; ++r) {
                const int row = m0 + wm + mi * 16 + r0 + r;
                float v = acc[mi][ni][r] + bv;
                if (ACT == 1) v = silu_f(v);
                if (ACT == 2) v = tanhf(v);
                if (RESID) v += R[(size_t)row * N + col];
                C[(size_t)row * N + col] = (OutT)v;
            }
        }
    }
}

// ------- Gaussian kernelized attention update: Q += sum_k S(G,mu,sig)*H -------
__global__ __launch_bounds__(256) void attn_kernel(
    float* __restrict__ Q, const float* __restrict__ mu_,
    const float* __restrict__ sig_, const float* __restrict__ x,
    const float* __restrict__ omega, const float* __restrict__ G,
    const float* __restrict__ phase) {
    __shared__ float cs[8][260];
    __shared__ float gs[8][260];
    const int tid = threadIdx.x;
    const int b   = blockIdx.x >> 1;
    const int t0  = (blockIdx.x & 1) * 256;
    const float x0 = x[2 * b], x1 = x[2 * b + 1];
    #pragma unroll
    for (int it = 0; it < 8; ++it) {
        int j = it * 256 + tid;            // 0..2047
        int e = t0 * 8 + j;                // flat (t,k) index
        float2 om = *(const float2*)(omega + 2 * e);
        float arg = fmaf(om.x, x0, fmaf(om.y, x1, phase[e]));
        cs[j & 7][j >> 3] = __cosf(arg);
        gs[j & 7][j >> 3] = G[e];
    }
    __syncthreads();
    const int idx = blockIdx.x * 256 + tid;   // = b*512 + t0 + tid
    float mu  = mu_[idx];
    float sig = sig_[idx];
    float inv = -0.5f * __builtin_amdgcn_rcpf(fmaf(sig, sig, EPS_SIG));
    float acc = 0.f;
    #pragma unroll
    for (int k = 0; k < 8; ++k) {
        float d = gs[k][tid] - mu;
        acc = fmaf(__expf(d * d * inv), cs[k][tid], acc);
    }
    Q[idx] += acc;
}

// ---------------- readout: out[b] = silu(Q[b,:]) . ro_w + ro_b ----------------
__global__ __launch_bounds__(256) void readout_kernel(
    const float* __restrict__ Q, const float* __restrict__ row_,
    const float* __restrict__ rob, float* __restrict__ out) {
    int lane = threadIdx.x & 63;
    int row  = blockIdx.x * 4 + (threadIdx.x >> 6);
    const float* qr = Q + (size_t)row * TT;
    float acc = 0.f;
    #pragma unroll
    for (int i = 0; i < 8; ++i) {
        int t = lane * 8 + i;
        acc = fmaf(silu_f(qr[t]), row_[t], acc);
    }
    #pragma unroll
    for (int off = 32; off > 0; off >>= 1) acc += __shfl_down(acc, off);
    if (lane == 0) out[row] = acc + rob[0];
}

} // namespace

extern "C" void kernel_launch(void* const* d_in, const int* in_sizes, int n_in,
                              void* d_out, int out_size, void* d_ws, size_t ws_size,
                              hipStream_t stream) {
    const float* x     = (const float*)d_in[0];
    const float* omega = (const float*)d_in[1];
    const float* G     = (const float*)d_in[2];
    const float* phase = (const float*)d_in[3];
    const float* l1_w  = (const float*)d_in[4];
    const float* l1_b  = (const float*)d_in[5];
    const float* mu_w  = (const float*)d_in[6];
    const float* mu_b  = (const float*)d_in[7];
    const float* sg_w  = (const float*)d_in[8];
    const float* sg_b  = (const float*)d_in[9];
    const float* alqg  = (const float*)d_in[10];
    const float* alqb  = (const float*)d_in[11];
    const float* alfg  = (const float*)d_in[12];
    const float* alfb  = (const float*)d_in[13];
    const float* a_w1  = (const float*)d_in[14];
    const float* a_b1  = (const float*)d_in[15];
    const float* a_w2  = (const float*)d_in[16];
    const float* a_b2  = (const float*)d_in[17];
    const float* mln_g = (const float*)d_in[18];
    const float* mln_b = (const float*)d_in[19];
    const float* m_w1  = (const float*)d_in[20];
    const float* m_b1  = (const float*)d_in[21];
    const float* m_w2  = (const float*)d_in[22];
    const float* m_b2  = (const float*)d_in[23];
    const float* ro_w  = (const float*)d_in[24];
    const float* ro_b  = (const float*)d_in[25];

    // ---- workspace layout (total 100,663,296 B == round-1 proven footprint) ----
    char* ws = (char*)d_ws;
    float*     Q    = (float*)ws;                          // 16 MB  [B,T] fp32
    _Float16*  h_hi = (_Float16*)(ws + 16777216);          //  8 MB  [B,T] f16
    _Float16*  h_lo = (_Float16*)(ws + 25165824);          //  8 MB  [B,T] f16
    _Float16*  mid  = (_Float16*)(ws + 33554432);          // 32 MB  [B,F] f16
    float*     mu   = (float*)(ws + 33554432);             // alias on mid
    float*     sig  = (float*)(ws + 50331648);             // alias on mid
    _Float16*  wbuf = (_Float16*)(ws + 67108864);          // 32 MB  f16 weights

    _Float16* muw_hi = wbuf;                     // 4*512*512
    _Float16* muw_lo = muw_hi + 1048576;
    _Float16* sgw_hi = muw_lo + 1048576;
    _Float16* sgw_lo = sgw_hi + 1048576;
    _Float16* aw1    = sgw_lo + 1048576;         // 4*2048*512
    _Float16* aw2    = aw1 + 4194304;
    _Float16* mw1    = aw2 + 4194304;            // 2*2048*512
    _Float16* mw2    = mw1 + 2097152;

    dim3 blk(256);

    // weight conversion (re-done every call; inputs are re-poisoned by harness)
    cvt_kernel<true ><<<1024, blk, 0, stream>>>(mu_w, muw_hi, muw_lo, 1048576);
    cvt_kernel<true ><<<1024, blk, 0, stream>>>(sg_w, sgw_hi, sgw_lo, 1048576);
    cvt_kernel<false><<<4096, blk, 0, stream>>>(a_w1, aw1, nullptr, 4194304);
    cvt_kernel<false><<<4096, blk, 0, stream>>>(a_w2, aw2, nullptr, 4194304);
    cvt_kernel<false><<<2048, blk, 0, stream>>>(m_w1, mw1, nullptr, 2097152);
    cvt_kernel<false><<<2048, blk, 0, stream>>>(m_w2, mw2, nullptr, 2097152);

    tok_kernel<<<BB * TT / 256, blk, 0, stream>>>(x, l1_w, l1_b, Q);

    for (int i = 0; i < 4; ++i) {
        ln_kernel<true><<<BB / 4, blk, 0, stream>>>(
            Q, alqg + i * TT, alqb + i * TT, h_hi, h_lo);
        gemm16_kernel<64, 2, false, true, float><<<dim3(BB / 128, TT / 64), blk, 0, stream>>>(
            h_hi, h_lo, muw_hi + (size_t)i * 262144, muw_lo + (size_t)i * 262144,
            mu_b + i * TT, nullptr, mu, TT, TT);
        gemm16_kernel<64, 0, false, true, float><<<dim3(BB / 128, TT / 64), blk, 0, stream>>>(
            h_hi, h_lo, sgw_hi + (size_t)i * 262144, sgw_lo + (size_t)i * 262144,
            sg_b + i * TT, nullptr, sig, TT, TT);
        attn_kernel<<<BB * TT / 256, blk, 0, stream>>>(Q, mu, sig, x, omega, G, phase);
        ln_kernel<false><<<BB / 4, blk, 0, stream>>>(
            Q, alfg + i * TT, alfb + i * TT, h_hi, nullptr);
        gemm16_kernel<128, 1, false, false, _Float16><<<dim3(BB / 128, FF / 128), blk, 0, stream>>>(
            h_hi, nullptr, aw1 + (size_t)i * 1048576, nullptr,
            a_b1 + i * FF, nullptr, mid, FF, TT);
        gemm16_kernel<64, 0, true, false, float><<<dim3(BB / 128, TT / 64), blk, 0, stream>>>(
            mid, nullptr, aw2 + (size_t)i * 1048576, nullptr,
            a_b2 + i * TT, Q, Q, TT, FF);
    }
    for (int i = 0; i < 2; ++i) {
        ln_kernel<false><<<BB / 4, blk, 0, stream>>>(
            Q, mln_g + i * TT, mln_b + i * TT, h_hi, nullptr);
        gemm16_kernel<128, 1, false, false, _Float16><<<dim3(BB / 128, FF / 128), blk, 0, stream>>>(
            h_hi, nullptr, mw1 + (size_t)i * 1048576, nullptr,
            m_b1 + i * FF, nullptr, mid, FF, TT);
        gemm16_kernel<64, 0, true, false, float><<<dim3(BB / 128, TT / 64), blk, 0, stream>>>(
            mid, nullptr, mw2 + (size_t)i * 1048576, nullptr,
            m_b2 + i * TT, Q, Q, TT, FF);
    }

    readout_kernel<<<BB / 4, blk, 0, stream>>>(Q, ro_w, ro_b, (float*)d_out);
}